// Round 7
// baseline (312.237 us; speedup 1.0000x reference)
//
#include <hip/hip_runtime.h>
#include <stdint.h>

typedef _Float16 f16;
typedef _Float16 half8 __attribute__((ext_vector_type(8)));
typedef _Float16 half4 __attribute__((ext_vector_type(4)));
typedef __fp16 fp16x2 __attribute__((ext_vector_type(2)));
typedef float f32x4 __attribute__((ext_vector_type(4)));
typedef float f32x16 __attribute__((ext_vector_type(16)));
typedef uint32_t u32x4 __attribute__((ext_vector_type(4)));

static constexpr int Bsz = 2, S = 2048, E = 2048, H = 16, D = 128;
static constexpr int M = Bsz * S;        // 4096
static constexpr int N_QKV = 3 * H * D;  // 6144
static constexpr int HD = H * D;         // 2048

__device__ __forceinline__ void gload_lds16(const void* gp, void* lp) {
  __builtin_amdgcn_global_load_lds(
      (const __attribute__((address_space(1))) uint32_t*)(uintptr_t)gp,
      (__attribute__((address_space(3))) uint32_t*)(uint32_t)(uintptr_t)lp,
      16, 0, 0);
}

__device__ __forceinline__ uint32_t pkrtz(float a, float b) {
  fp16x2 r = __builtin_amdgcn_cvt_pkrtz(a, b);
  return __builtin_bit_cast(uint32_t, r);
}

// ---------- f32 -> f16 cast ----------
__global__ void cast_f32_f16(const float* __restrict__ in, f16* __restrict__ out) {
  size_t i = (size_t)(blockIdx.x * 256 + threadIdx.x) * 8;
  float4 a = *(const float4*)&in[i];
  float4 b = *(const float4*)&in[i + 4];
  half8 h;
  h[0] = (f16)a.x; h[1] = (f16)a.y; h[2] = (f16)a.z; h[3] = (f16)a.w;
  h[4] = (f16)b.x; h[5] = (f16)b.y; h[6] = (f16)b.z; h[7] = (f16)b.w;
  *(half8*)&out[i] = h;
}

// ---------- transpose 2048x2048 f32 [k][n] -> f16 [n][k] ----------
__global__ void transpose_cast(const float* __restrict__ wq, const float* __restrict__ wk,
                               const float* __restrict__ wv, const float* __restrict__ wo,
                               f16* __restrict__ wt, f16* __restrict__ wot) {
  __shared__ float tile[32][33];
  int z = blockIdx.z;
  const float* src = (z == 0) ? wq : (z == 1) ? wk : (z == 2) ? wv : wo;
  f16* dst = (z == 3) ? wot : wt + (size_t)z * E * HD;
  int bx = blockIdx.x * 32, by = blockIdx.y * 32;
  int tx = threadIdx.x, ty = threadIdx.y;
#pragma unroll
  for (int r = 0; r < 4; ++r)
    tile[ty + r * 8][tx] = src[(size_t)(by + ty + r * 8) * 2048 + bx + tx];
  __syncthreads();
#pragma unroll
  for (int r = 0; r < 4; ++r)
    dst[(size_t)(bx + ty + r * 8) * 2048 + by + tx] = (f16)tile[tx][ty + r * 8];
}

// ---------- QKV GEMM (128x128, BK=32, 2-phase) + FUSED rope/split/v-transpose ----------
// bn 0..15: q head bn -> rope -> Qb[bh][s][d]
// bn 16..31: k head bn-16 -> rope -> Kb[bh][s][d]
// bn 32..47: v head bn-32 -> direct transposed store VtG[bh][d][s]
__global__ __launch_bounds__(256, 4) void qkv_fused(const f16* __restrict__ A,
                                                    const f16* __restrict__ Bt,
                                                    const float* __restrict__ cosb,
                                                    const float* __restrict__ sinb,
                                                    f16* __restrict__ Qb,
                                                    f16* __restrict__ Kb,
                                                    f16* __restrict__ VtG) {
  __shared__ f16 lds[16384];  // 32 KB: loop uses [0..8191] (As,Bs); epilogue T[128][128]
  f16* As = lds;
  f16* Bs = lds + 4096;
  const int Kk = E;
  const int t = threadIdx.x, l = t & 63;
  const int wm = (t >> 7) & 1, wn = (t >> 6) & 1;
  const int bm = blockIdx.x, bn = blockIdx.y;
  const int lr = l & 15, g = l >> 4;
  const int srow = t >> 2;
  const int schunk = t & 3;
  const int scol = ((schunk ^ (srow & 3)) * 8);
  const size_t abase = (size_t)(bm * 128 + srow) * Kk;
  const size_t bbase = (size_t)(bn * 128 + srow) * Kk;
  f32x4 acc[4][4] = {};
  for (int k0 = 0; k0 < Kk; k0 += 32) {
    __syncthreads();
    gload_lds16(&A[abase + k0 + scol], &As[t * 8]);
    gload_lds16(&A[abase + (size_t)64 * Kk + k0 + scol], &As[2048 + t * 8]);
    gload_lds16(&Bt[bbase + k0 + scol], &Bs[t * 8]);
    gload_lds16(&Bt[bbase + (size_t)64 * Kk + k0 + scol], &Bs[2048 + t * 8]);
    __syncthreads();
    half8 af[4], bf[4];
#pragma unroll
    for (int i = 0; i < 4; ++i) {
      int ra = wm * 64 + i * 16 + lr;
      int rb = wn * 64 + i * 16 + lr;
      af[i] = *(const half8*)&As[ra * 32 + ((g ^ (ra & 3)) * 8)];
      bf[i] = *(const half8*)&Bs[rb * 32 + ((g ^ (rb & 3)) * 8)];
    }
#pragma unroll
    for (int i = 0; i < 4; ++i)
#pragma unroll
      for (int j = 0; j < 4; ++j)
        acc[i][j] = __builtin_amdgcn_mfma_f32_16x16x32_f16(af[i], bf[j], acc[i][j], 0, 0, 0);
  }

  const int bt = bn >> 4;       // 0=q 1=k 2=v
  const int h = bn & 15;
  const int b = bm >> 4;        // 128-row blocks: 16 per batch
  const int bh = b * 16 + h;
  const int sblk = (bm & 15) * 128;  // s-offset of this block within sequence

  if (bt == 2) {
    // ---- V: direct reg -> VtG[bh][d][s] (r gives 4 consecutive s) ----
#pragma unroll
    for (int j = 0; j < 4; ++j) {
      int d = wn * 64 + j * 16 + lr;
      size_t rowb = ((size_t)bh * D + d) * S;
#pragma unroll
      for (int i = 0; i < 4; ++i) {
        int s0 = sblk + wm * 64 + i * 16 + g * 4;
        half4 h4;
#pragma unroll
        for (int r = 0; r < 4; ++r) h4[r] = (f16)acc[i][j][r];
        *(half4*)&VtG[rowb + s0] = h4;
      }
    }
  } else {
    // ---- Q/K: acc -> LDS T[128][128] f16, then rope + coalesced store ----
    __syncthreads();  // all waves done reading As/Bs
#pragma unroll
    for (int i = 0; i < 4; ++i)
#pragma unroll
      for (int j = 0; j < 4; ++j) {
        int row = wm * 64 + i * 16 + g * 4;
        int col = wn * 64 + j * 16 + lr;
#pragma unroll
        for (int r = 0; r < 4; ++r) lds[(row + r) * 128 + col] = (f16)acc[i][j][r];
      }
    __syncthreads();
    f16* Dst = (bt == 0) ? Qb : Kb;
    const int r2 = t >> 1;           // local row 0..127
    const int sg = sblk + r2;        // s within sequence
    const size_t obase = ((size_t)bh * S + sg) * D;
    const size_t cbase = (size_t)sg * D;
#pragma unroll
    for (int k = 0; k < 4; ++k) {
      const int dd0 = (t & 1) * 32 + k * 8;
#pragma unroll
      for (int half = 0; half < 2; ++half) {
        const int dd = dd0 + half * 4;
        float4 cl = *(const float4*)&cosb[cbase + dd];
        float4 ch = *(const float4*)&cosb[cbase + dd + 64];
        float4 sl = *(const float4*)&sinb[cbase + dd];
        float4 sh = *(const float4*)&sinb[cbase + dd + 64];
        half4 lo = *(half4*)&lds[r2 * 128 + dd];
        half4 hv = *(half4*)&lds[r2 * 128 + dd + 64];
        half4 olo, ohi;
        olo[0] = (f16)((float)lo[0] * cl.x - (float)hv[0] * sl.x);
        olo[1] = (f16)((float)lo[1] * cl.y - (float)hv[1] * sl.y);
        olo[2] = (f16)((float)lo[2] * cl.z - (float)hv[2] * sl.z);
        olo[3] = (f16)((float)lo[3] * cl.w - (float)hv[3] * sl.w);
        ohi[0] = (f16)((float)hv[0] * ch.x + (float)lo[0] * sh.x);
        ohi[1] = (f16)((float)hv[1] * ch.y + (float)lo[1] * sh.y);
        ohi[2] = (f16)((float)hv[2] * ch.z + (float)lo[2] * sh.z);
        ohi[3] = (f16)((float)hv[3] * ch.w + (float)lo[3] * sh.w);
        *(half4*)&Dst[obase + dd] = olo;
        *(half4*)&Dst[obase + dd + 64] = ohi;
      }
    }
  }
}

// ---------- plain GEMM (out-proj): A[M][K] f16 x Bt[N][K] -> C f32 ----------
template <typename OutT>
__global__ __launch_bounds__(256, 4) void gemm_bt(const f16* __restrict__ A,
                                                  const f16* __restrict__ Bt,
                                                  OutT* __restrict__ C,
                                                  int Mm, int Nn, int Kk) {
  __shared__ f16 As[128 * 32];
  __shared__ f16 Bs[128 * 32];
  const int t = threadIdx.x, l = t & 63;
  const int wm = (t >> 7) & 1, wn = (t >> 6) & 1;
  const int bm = blockIdx.x, bn = blockIdx.y;
  const int lr = l & 15, g = l >> 4;
  const int srow = t >> 2;
  const int schunk = t & 3;
  const int scol = ((schunk ^ (srow & 3)) * 8);
  const size_t abase = (size_t)(bm * 128 + srow) * Kk;
  const size_t bbase = (size_t)(bn * 128 + srow) * Kk;
  f32x4 acc[4][4] = {};
  for (int k0 = 0; k0 < Kk; k0 += 32) {
    __syncthreads();
    gload_lds16(&A[abase + k0 + scol], &As[t * 8]);
    gload_lds16(&A[abase + (size_t)64 * Kk + k0 + scol], &As[2048 + t * 8]);
    gload_lds16(&Bt[bbase + k0 + scol], &Bs[t * 8]);
    gload_lds16(&Bt[bbase + (size_t)64 * Kk + k0 + scol], &Bs[2048 + t * 8]);
    __syncthreads();
    half8 af[4], bf[4];
#pragma unroll
    for (int i = 0; i < 4; ++i) {
      int ra = wm * 64 + i * 16 + lr;
      int rb = wn * 64 + i * 16 + lr;
      af[i] = *(const half8*)&As[ra * 32 + ((g ^ (ra & 3)) * 8)];
      bf[i] = *(const half8*)&Bs[rb * 32 + ((g ^ (rb & 3)) * 8)];
    }
#pragma unroll
    for (int i = 0; i < 4; ++i)
#pragma unroll
      for (int j = 0; j < 4; ++j)
        acc[i][j] = __builtin_amdgcn_mfma_f32_16x16x32_f16(af[i], bf[j], acc[i][j], 0, 0, 0);
  }
#pragma unroll
  for (int i = 0; i < 4; ++i)
#pragma unroll
    for (int j = 0; j < 4; ++j) {
      int row = bm * 128 + wm * 64 + i * 16 + g * 4;
      int col = bn * 128 + wn * 64 + j * 16 + lr;
#pragma unroll
      for (int r = 0; r < 4; ++r)
        C[(size_t)(row + r) * Nn + col] = (OutT)acc[i][j][r];
    }
}

// ---------- flash attention: 32x32x16, swapped operands ----------
__device__ __forceinline__ void stage_kv(const f16* __restrict__ Kg, const f16* __restrict__ Vg,
                                         f16* KsB, f16* VsB, int t, int kv) {
#pragma unroll
  for (int rnd = 0; rnd < 4; ++rnd) {
    int row = rnd * 16 + (t >> 4);
    int c = t & 15;
    gload_lds16(&Kg[(size_t)(kv + row) * D + ((c ^ (row & 7)) * 8)], &KsB[rnd * 2048 + t * 8]);
  }
#pragma unroll
  for (int rnd = 0; rnd < 4; ++rnd) {
    int row = rnd * 32 + (t >> 3);
    int c = t & 7;
    gload_lds16(&Vg[(size_t)row * S + kv + ((c ^ (row & 7)) * 8)], &VsB[rnd * 2048 + t * 8]);
  }
}

__global__ __launch_bounds__(256, 2) void flash_attn2(const f16* __restrict__ Q,
                                                      const f16* __restrict__ K,
                                                      const f16* __restrict__ Vt,
                                                      f16* __restrict__ O) {
  __shared__ f16 lds[2][16384];
  const int t = threadIdx.x, l = t & 63, w = t >> 6;
  const int c = l & 31, hi = l >> 5;
  int bid = blockIdx.x;
  bid = (bid & 7) * 64 + (bid >> 3);
  const int bh = bid >> 4, qt = bid & 15;
  const size_t baseQ = (size_t)bh * S * D;
  const f16* Kg = K + baseQ;
  const f16* Vg = Vt + (size_t)bh * D * S;
  const int q0 = qt * 128 + w * 32;
  half8 qf[8];
#pragma unroll
  for (int dc = 0; dc < 8; ++dc)
    qf[dc] = *(const half8*)&Q[baseQ + (size_t)(q0 + c) * D + dc * 16 + hi * 8];
  f32x16 o[4] = {};
  float m = -3.0e38f, ssum = 0.f;

  stage_kv(Kg, Vg, &lds[0][0], &lds[0][8192], t, 0);
  __syncthreads();

  for (int it = 0; it < S / 64; ++it) {
    const int cur = it & 1;
    const f16* KsB = &lds[cur][0];
    const f16* VsB = &lds[cur][8192];
    if (it + 1 < S / 64) stage_kv(Kg, Vg, &lds[cur ^ 1][0], &lds[cur ^ 1][8192], t, (it + 1) * 64);

    f32x16 s0 = {}, s1 = {};
    __builtin_amdgcn_s_setprio(1);
#pragma unroll
    for (int dc = 0; dc < 8; ++dc) {
      const int r0 = c, r1 = 32 + c;
      half8 kf0 = *(const half8*)&KsB[r0 * 128 + (((2 * dc + hi) ^ (r0 & 7)) * 8)];
      half8 kf1 = *(const half8*)&KsB[r1 * 128 + (((2 * dc + hi) ^ (r1 & 7)) * 8)];
      s0 = __builtin_amdgcn_mfma_f32_32x32x16_f16(kf0, qf[dc], s0, 0, 0, 0);
      s1 = __builtin_amdgcn_mfma_f32_32x32x16_f16(kf1, qf[dc], s1, 0, 0, 0);
    }
    __builtin_amdgcn_s_setprio(0);

    float tm = s0[0];
#pragma unroll
    for (int r = 1; r < 16; ++r) tm = fmaxf(tm, s0[r]);
#pragma unroll
    for (int r = 0; r < 16; ++r) tm = fmaxf(tm, s1[r]);
    tm = fmaxf(tm, __shfl_xor(tm, 32));
    float mn = fmaxf(m, tm);
    float corr = __expf(m - mn);
    m = mn;
    float ts = 0.f;
#pragma unroll
    for (int r = 0; r < 16; ++r) { s0[r] = __expf(s0[r] - mn); ts += s0[r]; }
#pragma unroll
    for (int r = 0; r < 16; ++r) { s1[r] = __expf(s1[r] - mn); ts += s1[r]; }
    ts += __shfl_xor(ts, 32);
    ssum = ssum * corr + ts;
#pragma unroll
    for (int dt = 0; dt < 4; ++dt)
#pragma unroll
      for (int r = 0; r < 16; ++r) o[dt][r] *= corr;

    half8 pf[4];
#pragma unroll
    for (int ks = 0; ks < 4; ++ks) {
      const int B0 = 2 * (ks & 1), B1 = B0 + 1;
      uint32_t X0, X1, Y0, Y1;
      if (ks < 2) {
        X0 = pkrtz(s0[4 * B0 + 0], s0[4 * B0 + 1]);
        X1 = pkrtz(s0[4 * B0 + 2], s0[4 * B0 + 3]);
        Y0 = pkrtz(s0[4 * B1 + 0], s0[4 * B1 + 1]);
        Y1 = pkrtz(s0[4 * B1 + 2], s0[4 * B1 + 3]);
      } else {
        X0 = pkrtz(s1[4 * B0 + 0], s1[4 * B0 + 1]);
        X1 = pkrtz(s1[4 * B0 + 2], s1[4 * B0 + 3]);
        Y0 = pkrtz(s1[4 * B1 + 0], s1[4 * B1 + 1]);
        Y1 = pkrtz(s1[4 * B1 + 2], s1[4 * B1 + 3]);
      }
      asm volatile("v_permlane32_swap_b32 %0, %1" : "+v"(X0), "+v"(Y0));
      asm volatile("v_permlane32_swap_b32 %0, %1" : "+v"(X1), "+v"(Y1));
      u32x4 pw; pw[0] = X0; pw[1] = X1; pw[2] = Y0; pw[3] = Y1;
      pf[ks] = __builtin_bit_cast(half8, pw);
    }

    __builtin_amdgcn_s_setprio(1);
#pragma unroll
    for (int dt = 0; dt < 4; ++dt) {
      const int row = dt * 32 + c;
#pragma unroll
      for (int ks = 0; ks < 4; ++ks) {
        half8 vf = *(const half8*)&VsB[row * 64 + (((2 * ks + hi) ^ (row & 7)) * 8)];
        o[dt] = __builtin_amdgcn_mfma_f32_32x32x16_f16(vf, pf[ks], o[dt], 0, 0, 0);
      }
    }
    __builtin_amdgcn_s_setprio(0);
    __syncthreads();
  }

  const float inv = 1.f / ssum;
  const int b = bh >> 4, h = bh & 15;
  const size_t orow = ((size_t)(b * S + q0 + c)) * HD + h * D;
#pragma unroll
  for (int dt = 0; dt < 4; ++dt)
#pragma unroll
    for (int b2 = 0; b2 < 4; ++b2) {
      half4 h4;
#pragma unroll
      for (int a = 0; a < 4; ++a) h4[a] = (f16)(o[dt][4 * b2 + a] * inv);
      *(half4*)&O[orow + dt * 32 + 8 * b2 + 4 * hi] = h4;
    }
}

extern "C" void kernel_launch(void* const* d_in, const int* in_sizes, int n_in,
                              void* d_out, int out_size, void* d_ws, size_t ws_size,
                              hipStream_t stream) {
  (void)in_sizes; (void)n_in; (void)out_size; (void)ws_size;
  const float* hs = (const float*)d_in[0];
  const float* cosb = (const float*)d_in[1];
  const float* sinb = (const float*)d_in[2];
  const float* wq = (const float*)d_in[3];
  const float* wk = (const float*)d_in[4];
  const float* wv = (const float*)d_in[5];
  const float* wo = (const float*)d_in[6];
  float* out = (float*)d_out;
  char* ws = (char*)d_ws;
  f16* hs16 = (f16*)(ws);                 // 16M; dead after qkv_fused
  f16* attn = (f16*)(ws);                 // 16M; alias (written by flash)
  f16* wt   = (f16*)(ws + (16u << 20));   // 24M  [6144][2048]
  f16* wot  = (f16*)(ws + (40u << 20));   // 8M   [2048][2048]
  f16* Qb   = (f16*)(ws + (48u << 20));   // 16M  [32][2048][128]
  f16* Kb   = (f16*)(ws + (64u << 20));   // 16M  [32][2048][128]
  f16* VtG  = (f16*)(ws + (80u << 20));   // 16M  [32][128][2048]

  cast_f32_f16<<<dim3(4096), dim3(256), 0, stream>>>(hs, hs16);
  transpose_cast<<<dim3(64, 64, 4), dim3(32, 8), 0, stream>>>(wq, wk, wv, wo, wt, wot);
  qkv_fused<<<dim3(32, 48), dim3(256), 0, stream>>>(hs16, wt, cosb, sinb, Qb, Kb, VtG);
  flash_attn2<<<dim3(512), dim3(256), 0, stream>>>(Qb, Kb, VtG, attn);
  gemm_bt<float><<<dim3(32, 16), dim3(256), 0, stream>>>(attn, wot, out, M, E, HD);
}

// Round 8
// 304.281 us; speedup vs baseline: 1.0261x; 1.0261x over previous
//
#include <hip/hip_runtime.h>
#include <stdint.h>

typedef _Float16 f16;
typedef _Float16 half8 __attribute__((ext_vector_type(8)));
typedef _Float16 half4 __attribute__((ext_vector_type(4)));
typedef __fp16 fp16x2 __attribute__((ext_vector_type(2)));
typedef float f32x4 __attribute__((ext_vector_type(4)));
typedef float f32x16 __attribute__((ext_vector_type(16)));
typedef uint32_t u32x4 __attribute__((ext_vector_type(4)));

static constexpr int Bsz = 2, S = 2048, E = 2048, H = 16, D = 128;
static constexpr int M = Bsz * S;        // 4096
static constexpr int N_QKV = 3 * H * D;  // 6144
static constexpr int HD = H * D;         // 2048

__device__ __forceinline__ void gload_lds16(const void* gp, void* lp) {
  __builtin_amdgcn_global_load_lds(
      (const __attribute__((address_space(1))) uint32_t*)(uintptr_t)gp,
      (__attribute__((address_space(3))) uint32_t*)(uint32_t)(uintptr_t)lp,
      16, 0, 0);
}

__device__ __forceinline__ uint32_t pkrtz(float a, float b) {
  fp16x2 r = __builtin_amdgcn_cvt_pkrtz(a, b);
  return __builtin_bit_cast(uint32_t, r);
}

// ---------- f32 -> f16 cast ----------
__global__ void cast_f32_f16(const float* __restrict__ in, f16* __restrict__ out) {
  size_t i = (size_t)(blockIdx.x * 256 + threadIdx.x) * 8;
  float4 a = *(const float4*)&in[i];
  float4 b = *(const float4*)&in[i + 4];
  half8 h;
  h[0] = (f16)a.x; h[1] = (f16)a.y; h[2] = (f16)a.z; h[3] = (f16)a.w;
  h[4] = (f16)b.x; h[5] = (f16)b.y; h[6] = (f16)b.z; h[7] = (f16)b.w;
  *(half8*)&out[i] = h;
}

// ---------- transpose 2048x2048 f32 [k][n] -> f16 [n][k] ----------
__global__ void transpose_cast(const float* __restrict__ wq, const float* __restrict__ wk,
                               const float* __restrict__ wv, const float* __restrict__ wo,
                               f16* __restrict__ wt, f16* __restrict__ wot) {
  __shared__ float tile[32][33];
  int z = blockIdx.z;
  const float* src = (z == 0) ? wq : (z == 1) ? wk : (z == 2) ? wv : wo;
  f16* dst = (z == 3) ? wot : wt + (size_t)z * E * HD;
  int bx = blockIdx.x * 32, by = blockIdx.y * 32;
  int tx = threadIdx.x, ty = threadIdx.y;
#pragma unroll
  for (int r = 0; r < 4; ++r)
    tile[ty + r * 8][tx] = src[(size_t)(by + ty + r * 8) * 2048 + bx + tx];
  __syncthreads();
#pragma unroll
  for (int r = 0; r < 4; ++r)
    dst[(size_t)(bx + ty + r * 8) * 2048 + by + tx] = (f16)tile[tx][ty + r * 8];
}

// ---------- QKV GEMM + fused rope/split/v-transpose, register-only epilogue ----------
// wg = bn*32+bm (consecutive blocks share B panel), XCD-chunked.
// bn 0..15: Q head; 16..31: K head (SWAPPED mfma -> thread holds 4 consecutive d
//   at fixed s, rotate_half partner d+64 in same thread via wave-col remap);
// bn 32..47: V head (standard mfma -> 4 consecutive s at fixed d -> VtG).
__global__ __launch_bounds__(256, 4) void qkv_fused(const f16* __restrict__ A,
                                                    const f16* __restrict__ Bt,
                                                    const float* __restrict__ cosb,
                                                    const float* __restrict__ sinb,
                                                    f16* __restrict__ Qb,
                                                    f16* __restrict__ Kb,
                                                    f16* __restrict__ VtG) {
  __shared__ f16 As[4096];
  __shared__ f16 Bs[4096];
  const int Kk = E;
  const int t = threadIdx.x, l = t & 63;
  const int wm = (t >> 7) & 1, wn = (t >> 6) & 1;
  const int lr = l & 15, g = l >> 4;
  int bid = blockIdx.x;
  int wg = (bid & 7) * 192 + (bid >> 3);  // bijective: 1536 = 8*192
  const int bn = wg / 32, bm = wg % 32;
  const int srow = t >> 2;
  const int scol = (((t & 3) ^ (srow & 3)) * 8);
  const size_t abase = (size_t)(bm * 128 + srow) * Kk;
  const size_t bbase = (size_t)(bn * 128 + srow) * Kk;
  const int bt = bn >> 4;       // 0=q 1=k 2=v
  const int h = bn & 15;
  const int b = bm >> 4;
  const int bh = b * 16 + h;
  const int sblk = (bm & 15) * 128;
  f32x4 acc[4][4] = {};

  if (bt < 2) {
    // ---- Q/K: swapped-operand K-loop; wave cols {wn*32, +16, +64, +80} ----
    for (int k0 = 0; k0 < Kk; k0 += 32) {
      __syncthreads();
      gload_lds16(&A[abase + k0 + scol], &As[t * 8]);
      gload_lds16(&A[abase + (size_t)64 * Kk + k0 + scol], &As[2048 + t * 8]);
      gload_lds16(&Bt[bbase + k0 + scol], &Bs[t * 8]);
      gload_lds16(&Bt[bbase + (size_t)64 * Kk + k0 + scol], &Bs[2048 + t * 8]);
      __syncthreads();
      half8 af[4], bf[4];
#pragma unroll
      for (int i = 0; i < 4; ++i) {
        int ra = wm * 64 + i * 16 + lr;
        af[i] = *(const half8*)&As[ra * 32 + ((g ^ (ra & 3)) * 8)];
      }
#pragma unroll
      for (int j = 0; j < 4; ++j) {
        int rb = wn * 32 + (j & 1) * 16 + (j >> 1) * 64 + lr;
        bf[j] = *(const half8*)&Bs[rb * 32 + ((g ^ (rb & 3)) * 8)];
      }
#pragma unroll
      for (int i = 0; i < 4; ++i)
#pragma unroll
        for (int j = 0; j < 4; ++j)
          acc[i][j] = __builtin_amdgcn_mfma_f32_16x16x32_f16(bf[j], af[i], acc[i][j], 0, 0, 0);
    }
    // ---- rope in-register, coalesced half4 stores ----
    f16* Dst = (bt == 0) ? Qb : Kb;
#pragma unroll
    for (int i = 0; i < 4; ++i) {
      const int s = sblk + wm * 64 + i * 16 + lr;
      const size_t obase = ((size_t)bh * S + s) * D;
      const size_t cbase = (size_t)s * D;
#pragma unroll
      for (int j = 0; j < 2; ++j) {
        const int dlo = wn * 32 + j * 16 + g * 4;
        float4 cl = *(const float4*)&cosb[cbase + dlo];
        float4 ch = *(const float4*)&cosb[cbase + dlo + 64];
        float4 sl = *(const float4*)&sinb[cbase + dlo];
        float4 sh = *(const float4*)&sinb[cbase + dlo + 64];
        float cla[4] = {cl.x, cl.y, cl.z, cl.w}, cha[4] = {ch.x, ch.y, ch.z, ch.w};
        float sla[4] = {sl.x, sl.y, sl.z, sl.w}, sha[4] = {sh.x, sh.y, sh.z, sh.w};
        half4 olo, ohi;
#pragma unroll
        for (int r = 0; r < 4; ++r) {
          float xl = acc[i][j][r], xh = acc[i][j + 2][r];
          olo[r] = (f16)(xl * cla[r] - xh * sla[r]);
          ohi[r] = (f16)(xh * cha[r] + xl * sha[r]);
        }
        *(half4*)&Dst[obase + dlo] = olo;
        *(half4*)&Dst[obase + dlo + 64] = ohi;
      }
    }
  } else {
    // ---- V: standard K-loop; direct transposed store ----
    for (int k0 = 0; k0 < Kk; k0 += 32) {
      __syncthreads();
      gload_lds16(&A[abase + k0 + scol], &As[t * 8]);
      gload_lds16(&A[abase + (size_t)64 * Kk + k0 + scol], &As[2048 + t * 8]);
      gload_lds16(&Bt[bbase + k0 + scol], &Bs[t * 8]);
      gload_lds16(&Bt[bbase + (size_t)64 * Kk + k0 + scol], &Bs[2048 + t * 8]);
      __syncthreads();
      half8 af[4], bf[4];
#pragma unroll
      for (int i = 0; i < 4; ++i) {
        int ra = wm * 64 + i * 16 + lr;
        int rb = wn * 64 + i * 16 + lr;
        af[i] = *(const half8*)&As[ra * 32 + ((g ^ (ra & 3)) * 8)];
        bf[i] = *(const half8*)&Bs[rb * 32 + ((g ^ (rb & 3)) * 8)];
      }
#pragma unroll
      for (int i = 0; i < 4; ++i)
#pragma unroll
        for (int j = 0; j < 4; ++j)
          acc[i][j] = __builtin_amdgcn_mfma_f32_16x16x32_f16(af[i], bf[j], acc[i][j], 0, 0, 0);
    }
#pragma unroll
    for (int j = 0; j < 4; ++j) {
      int d = wn * 64 + j * 16 + lr;
      size_t rowb = ((size_t)bh * D + d) * S;
#pragma unroll
      for (int i = 0; i < 4; ++i) {
        int s0 = sblk + wm * 64 + i * 16 + g * 4;
        half4 h4;
#pragma unroll
        for (int r = 0; r < 4; ++r) h4[r] = (f16)acc[i][j][r];
        *(half4*)&VtG[rowb + s0] = h4;
      }
    }
  }
}

// ---------- plain GEMM (out-proj): A[M][K] f16 x Bt[N][K] -> C f32 ----------
template <typename OutT>
__global__ __launch_bounds__(256, 4) void gemm_bt(const f16* __restrict__ A,
                                                  const f16* __restrict__ Bt,
                                                  OutT* __restrict__ C,
                                                  int Mm, int Nn, int Kk) {
  __shared__ f16 As[128 * 32];
  __shared__ f16 Bs[128 * 32];
  const int t = threadIdx.x, l = t & 63;
  const int wm = (t >> 7) & 1, wn = (t >> 6) & 1;
  const int bm = blockIdx.x, bn = blockIdx.y;
  const int lr = l & 15, g = l >> 4;
  const int srow = t >> 2;
  const int schunk = t & 3;
  const int scol = ((schunk ^ (srow & 3)) * 8);
  const size_t abase = (size_t)(bm * 128 + srow) * Kk;
  const size_t bbase = (size_t)(bn * 128 + srow) * Kk;
  f32x4 acc[4][4] = {};
  for (int k0 = 0; k0 < Kk; k0 += 32) {
    __syncthreads();
    gload_lds16(&A[abase + k0 + scol], &As[t * 8]);
    gload_lds16(&A[abase + (size_t)64 * Kk + k0 + scol], &As[2048 + t * 8]);
    gload_lds16(&Bt[bbase + k0 + scol], &Bs[t * 8]);
    gload_lds16(&Bt[bbase + (size_t)64 * Kk + k0 + scol], &Bs[2048 + t * 8]);
    __syncthreads();
    half8 af[4], bf[4];
#pragma unroll
    for (int i = 0; i < 4; ++i) {
      int ra = wm * 64 + i * 16 + lr;
      int rb = wn * 64 + i * 16 + lr;
      af[i] = *(const half8*)&As[ra * 32 + ((g ^ (ra & 3)) * 8)];
      bf[i] = *(const half8*)&Bs[rb * 32 + ((g ^ (rb & 3)) * 8)];
    }
#pragma unroll
    for (int i = 0; i < 4; ++i)
#pragma unroll
      for (int j = 0; j < 4; ++j)
        acc[i][j] = __builtin_amdgcn_mfma_f32_16x16x32_f16(af[i], bf[j], acc[i][j], 0, 0, 0);
  }
#pragma unroll
  for (int i = 0; i < 4; ++i)
#pragma unroll
    for (int j = 0; j < 4; ++j) {
      int row = bm * 128 + wm * 64 + i * 16 + g * 4;
      int col = bn * 128 + wn * 64 + j * 16 + lr;
#pragma unroll
      for (int r = 0; r < 4; ++r)
        C[(size_t)(row + r) * Nn + col] = (OutT)acc[i][j][r];
    }
}

// ---------- flash attention: 32x32x16, swapped operands ----------
__device__ __forceinline__ void stage_kv(const f16* __restrict__ Kg, const f16* __restrict__ Vg,
                                         f16* KsB, f16* VsB, int t, int kv) {
#pragma unroll
  for (int rnd = 0; rnd < 4; ++rnd) {
    int row = rnd * 16 + (t >> 4);
    int c = t & 15;
    gload_lds16(&Kg[(size_t)(kv + row) * D + ((c ^ (row & 7)) * 8)], &KsB[rnd * 2048 + t * 8]);
  }
#pragma unroll
  for (int rnd = 0; rnd < 4; ++rnd) {
    int row = rnd * 32 + (t >> 3);
    int c = t & 7;
    gload_lds16(&Vg[(size_t)row * S + kv + ((c ^ (row & 7)) * 8)], &VsB[rnd * 2048 + t * 8]);
  }
}

__global__ __launch_bounds__(256, 2) void flash_attn2(const f16* __restrict__ Q,
                                                      const f16* __restrict__ K,
                                                      const f16* __restrict__ Vt,
                                                      f16* __restrict__ O) {
  __shared__ f16 lds[2][16384];
  const int t = threadIdx.x, l = t & 63, w = t >> 6;
  const int c = l & 31, hi = l >> 5;
  int bid = blockIdx.x;
  bid = (bid & 7) * 64 + (bid >> 3);
  const int bh = bid >> 4, qt = bid & 15;
  const size_t baseQ = (size_t)bh * S * D;
  const f16* Kg = K + baseQ;
  const f16* Vg = Vt + (size_t)bh * D * S;
  const int q0 = qt * 128 + w * 32;
  half8 qf[8];
#pragma unroll
  for (int dc = 0; dc < 8; ++dc)
    qf[dc] = *(const half8*)&Q[baseQ + (size_t)(q0 + c) * D + dc * 16 + hi * 8];
  f32x16 o[4] = {};
  float m = -3.0e38f, ssum = 0.f;

  stage_kv(Kg, Vg, &lds[0][0], &lds[0][8192], t, 0);
  __syncthreads();

  for (int it = 0; it < S / 64; ++it) {
    const int cur = it & 1;
    const f16* KsB = &lds[cur][0];
    const f16* VsB = &lds[cur][8192];
    if (it + 1 < S / 64) stage_kv(Kg, Vg, &lds[cur ^ 1][0], &lds[cur ^ 1][8192], t, (it + 1) * 64);

    f32x16 s0 = {}, s1 = {};
    __builtin_amdgcn_s_setprio(1);
#pragma unroll
    for (int dc = 0; dc < 8; ++dc) {
      const int r0 = c, r1 = 32 + c;
      half8 kf0 = *(const half8*)&KsB[r0 * 128 + (((2 * dc + hi) ^ (r0 & 7)) * 8)];
      half8 kf1 = *(const half8*)&KsB[r1 * 128 + (((2 * dc + hi) ^ (r1 & 7)) * 8)];
      s0 = __builtin_amdgcn_mfma_f32_32x32x16_f16(kf0, qf[dc], s0, 0, 0, 0);
      s1 = __builtin_amdgcn_mfma_f32_32x32x16_f16(kf1, qf[dc], s1, 0, 0, 0);
    }
    __builtin_amdgcn_s_setprio(0);

    float tm = s0[0];
#pragma unroll
    for (int r = 1; r < 16; ++r) tm = fmaxf(tm, s0[r]);
#pragma unroll
    for (int r = 0; r < 16; ++r) tm = fmaxf(tm, s1[r]);
    tm = fmaxf(tm, __shfl_xor(tm, 32));
    float mn = fmaxf(m, tm);
    float corr = __expf(m - mn);
    m = mn;
    float ts = 0.f;
#pragma unroll
    for (int r = 0; r < 16; ++r) { s0[r] = __expf(s0[r] - mn); ts += s0[r]; }
#pragma unroll
    for (int r = 0; r < 16; ++r) { s1[r] = __expf(s1[r] - mn); ts += s1[r]; }
    ts += __shfl_xor(ts, 32);
    ssum = ssum * corr + ts;
#pragma unroll
    for (int dt = 0; dt < 4; ++dt)
#pragma unroll
      for (int r = 0; r < 16; ++r) o[dt][r] *= corr;

    half8 pf[4];
#pragma unroll
    for (int ks = 0; ks < 4; ++ks) {
      const int B0 = 2 * (ks & 1), B1 = B0 + 1;
      uint32_t X0, X1, Y0, Y1;
      if (ks < 2) {
        X0 = pkrtz(s0[4 * B0 + 0], s0[4 * B0 + 1]);
        X1 = pkrtz(s0[4 * B0 + 2], s0[4 * B0 + 3]);
        Y0 = pkrtz(s0[4 * B1 + 0], s0[4 * B1 + 1]);
        Y1 = pkrtz(s0[4 * B1 + 2], s0[4 * B1 + 3]);
      } else {
        X0 = pkrtz(s1[4 * B0 + 0], s1[4 * B0 + 1]);
        X1 = pkrtz(s1[4 * B0 + 2], s1[4 * B0 + 3]);
        Y0 = pkrtz(s1[4 * B1 + 0], s1[4 * B1 + 1]);
        Y1 = pkrtz(s1[4 * B1 + 2], s1[4 * B1 + 3]);
      }
      asm volatile("v_permlane32_swap_b32 %0, %1" : "+v"(X0), "+v"(Y0));
      asm volatile("v_permlane32_swap_b32 %0, %1" : "+v"(X1), "+v"(Y1));
      u32x4 pw; pw[0] = X0; pw[1] = X1; pw[2] = Y0; pw[3] = Y1;
      pf[ks] = __builtin_bit_cast(half8, pw);
    }

    __builtin_amdgcn_s_setprio(1);
#pragma unroll
    for (int dt = 0; dt < 4; ++dt) {
      const int row = dt * 32 + c;
#pragma unroll
      for (int ks = 0; ks < 4; ++ks) {
        half8 vf = *(const half8*)&VsB[row * 64 + (((2 * ks + hi) ^ (row & 7)) * 8)];
        o[dt] = __builtin_amdgcn_mfma_f32_32x32x16_f16(vf, pf[ks], o[dt], 0, 0, 0);
      }
    }
    __builtin_amdgcn_s_setprio(0);
    __syncthreads();
  }

  const float inv = 1.f / ssum;
  const int b = bh >> 4, h = bh & 15;
  const size_t orow = ((size_t)(b * S + q0 + c)) * HD + h * D;
#pragma unroll
  for (int dt = 0; dt < 4; ++dt)
#pragma unroll
    for (int b2 = 0; b2 < 4; ++b2) {
      half4 h4;
#pragma unroll
      for (int a = 0; a < 4; ++a) h4[a] = (f16)(o[dt][4 * b2 + a] * inv);
      *(half4*)&O[orow + dt * 32 + 8 * b2 + 4 * hi] = h4;
    }
}

extern "C" void kernel_launch(void* const* d_in, const int* in_sizes, int n_in,
                              void* d_out, int out_size, void* d_ws, size_t ws_size,
                              hipStream_t stream) {
  (void)in_sizes; (void)n_in; (void)out_size; (void)ws_size;
  const float* hs = (const float*)d_in[0];
  const float* cosb = (const float*)d_in[1];
  const float* sinb = (const float*)d_in[2];
  const float* wq = (const float*)d_in[3];
  const float* wk = (const float*)d_in[4];
  const float* wv = (const float*)d_in[5];
  const float* wo = (const float*)d_in[6];
  float* out = (float*)d_out;
  char* ws = (char*)d_ws;
  f16* hs16 = (f16*)(ws);                 // 16M; dead after qkv_fused
  f16* attn = (f16*)(ws);                 // 16M; alias (written by flash)
  f16* wt   = (f16*)(ws + (16u << 20));   // 24M  [6144][2048]
  f16* wot  = (f16*)(ws + (40u << 20));   // 8M   [2048][2048]
  f16* Qb   = (f16*)(ws + (48u << 20));   // 16M  [32][2048][128]
  f16* Kb   = (f16*)(ws + (64u << 20));   // 16M  [32][2048][128]
  f16* VtG  = (f16*)(ws + (80u << 20));   // 16M  [32][128][2048]

  cast_f32_f16<<<dim3(4096), dim3(256), 0, stream>>>(hs, hs16);
  transpose_cast<<<dim3(64, 64, 4), dim3(32, 8), 0, stream>>>(wq, wk, wv, wo, wt, wot);
  qkv_fused<<<dim3(1536), dim3(256), 0, stream>>>(hs16, wt, cosb, sinb, Qb, Kb, VtG);
  flash_attn2<<<dim3(512), dim3(256), 0, stream>>>(Qb, Kb, VtG, attn);
  gemm_bt<float><<<dim3(32, 16), dim3(256), 0, stream>>>(attn, wot, out, M, E, HD);
}

// Round 9
// 298.915 us; speedup vs baseline: 1.0446x; 1.0180x over previous
//
#include <hip/hip_runtime.h>
#include <stdint.h>

typedef _Float16 f16;
typedef _Float16 half8 __attribute__((ext_vector_type(8)));
typedef _Float16 half4 __attribute__((ext_vector_type(4)));
typedef __fp16 fp16x2 __attribute__((ext_vector_type(2)));
typedef float f32x4 __attribute__((ext_vector_type(4)));
typedef float f32x16 __attribute__((ext_vector_type(16)));
typedef uint32_t u32x4 __attribute__((ext_vector_type(4)));

static constexpr int Bsz = 2, S = 2048, E = 2048, H = 16, D = 128;
static constexpr int M = Bsz * S;        // 4096
static constexpr int N_QKV = 3 * H * D;  // 6144
static constexpr int HD = H * D;         // 2048

__device__ __forceinline__ void gload_lds16(const void* gp, void* lp) {
  __builtin_amdgcn_global_load_lds(
      (const __attribute__((address_space(1))) uint32_t*)(uintptr_t)gp,
      (__attribute__((address_space(3))) uint32_t*)(uint32_t)(uintptr_t)lp,
      16, 0, 0);
}

__device__ __forceinline__ uint32_t pkrtz(float a, float b) {
  fp16x2 r = __builtin_amdgcn_cvt_pkrtz(a, b);
  return __builtin_bit_cast(uint32_t, r);
}

// ---------- f32 -> f16 cast ----------
__global__ void cast_f32_f16(const float* __restrict__ in, f16* __restrict__ out) {
  size_t i = (size_t)(blockIdx.x * 256 + threadIdx.x) * 8;
  float4 a = *(const float4*)&in[i];
  float4 b = *(const float4*)&in[i + 4];
  half8 h;
  h[0] = (f16)a.x; h[1] = (f16)a.y; h[2] = (f16)a.z; h[3] = (f16)a.w;
  h[4] = (f16)b.x; h[5] = (f16)b.y; h[6] = (f16)b.z; h[7] = (f16)b.w;
  *(half8*)&out[i] = h;
}

// ---------- transpose 2048x2048 f32 [k][n] -> f16 [n][k] ----------
__global__ void transpose_cast(const float* __restrict__ wq, const float* __restrict__ wk,
                               const float* __restrict__ wv, const float* __restrict__ wo,
                               f16* __restrict__ wt, f16* __restrict__ wot) {
  __shared__ float tile[32][33];
  int z = blockIdx.z;
  const float* src = (z == 0) ? wq : (z == 1) ? wk : (z == 2) ? wv : wo;
  f16* dst = (z == 3) ? wot : wt + (size_t)z * E * HD;
  int bx = blockIdx.x * 32, by = blockIdx.y * 32;
  int tx = threadIdx.x, ty = threadIdx.y;
#pragma unroll
  for (int r = 0; r < 4; ++r)
    tile[ty + r * 8][tx] = src[(size_t)(by + ty + r * 8) * 2048 + bx + tx];
  __syncthreads();
#pragma unroll
  for (int r = 0; r < 4; ++r)
    dst[(size_t)(bx + ty + r * 8) * 2048 + by + tx] = (f16)tile[tx][ty + r * 8];
}

// Staging of one 32-k section (identical layout to the proven BK=32 buffer).
#define STAGE4(PTR, BASE, KOFF, DST)                                       \
  gload_lds16(&PTR[BASE + (KOFF) + scol], &DST[t * 8]);                    \
  gload_lds16(&PTR[BASE + (size_t)64 * Kk + (KOFF) + scol], &DST[2048 + t * 8]);

// ---------- QKV GEMM (128x128, BK=64 two-section) + fused rope/split/v-transpose ----------
// bn 0..15: Q head; 16..31: K head (SWAPPED mfma -> 4 consecutive d at fixed s,
//   rotate_half partner in-register); bn 32..47: V head (direct transposed store).
__global__ __launch_bounds__(256, 4) void qkv_fused(const f16* __restrict__ A,
                                                    const f16* __restrict__ Bt,
                                                    const float* __restrict__ cosb,
                                                    const float* __restrict__ sinb,
                                                    f16* __restrict__ Qb,
                                                    f16* __restrict__ Kb,
                                                    f16* __restrict__ VtG) {
  __shared__ f16 As[8192];  // [2 sections][128][32]
  __shared__ f16 Bs[8192];
  const int Kk = E;
  const int t = threadIdx.x, l = t & 63;
  const int wm = (t >> 7) & 1, wn = (t >> 6) & 1;
  const int lr = l & 15, g = l >> 4;
  int bid = blockIdx.x;
  int wg = (bid & 7) * 192 + (bid >> 3);  // bijective: 1536 = 8*192
  const int bn = wg / 32, bm = wg % 32;
  const int srow = t >> 2;
  const int scol = (((t & 3) ^ (srow & 3)) * 8);
  const size_t abase = (size_t)(bm * 128 + srow) * Kk;
  const size_t bbase = (size_t)(bn * 128 + srow) * Kk;
  const int bt = bn >> 4;       // 0=q 1=k 2=v
  const int h = bn & 15;
  const int b = bm >> 4;
  const int bh = b * 16 + h;
  const int sblk = (bm & 15) * 128;
  f32x4 acc[4][4] = {};

  if (bt < 2) {
    // ---- Q/K: swapped-operand K-loop; wave cols {wn*32, +16, +64, +80} ----
    for (int k0 = 0; k0 < Kk; k0 += 64) {
      __syncthreads();
      STAGE4(A, abase, k0, As);
      STAGE4(Bt, bbase, k0, Bs);
      STAGE4(A, abase, k0 + 32, (As + 4096));
      STAGE4(Bt, bbase, k0 + 32, (Bs + 4096));
      __syncthreads();
#pragma unroll
      for (int kh = 0; kh < 2; ++kh) {
        const int so = kh * 4096;
        half8 af[4], bf[4];
#pragma unroll
        for (int i = 0; i < 4; ++i) {
          int ra = wm * 64 + i * 16 + lr;
          af[i] = *(const half8*)&As[so + ra * 32 + ((g ^ (ra & 3)) * 8)];
        }
#pragma unroll
        for (int j = 0; j < 4; ++j) {
          int rb = wn * 32 + (j & 1) * 16 + (j >> 1) * 64 + lr;
          bf[j] = *(const half8*)&Bs[so + rb * 32 + ((g ^ (rb & 3)) * 8)];
        }
#pragma unroll
        for (int i = 0; i < 4; ++i)
#pragma unroll
          for (int j = 0; j < 4; ++j)
            acc[i][j] = __builtin_amdgcn_mfma_f32_16x16x32_f16(bf[j], af[i], acc[i][j], 0, 0, 0);
      }
    }
    // ---- rope in-register, coalesced half4 stores ----
    f16* Dst = (bt == 0) ? Qb : Kb;
#pragma unroll
    for (int i = 0; i < 4; ++i) {
      const int s = sblk + wm * 64 + i * 16 + lr;
      const size_t obase = ((size_t)bh * S + s) * D;
      const size_t cbase = (size_t)s * D;
#pragma unroll
      for (int j = 0; j < 2; ++j) {
        const int dlo = wn * 32 + j * 16 + g * 4;
        float4 cl = *(const float4*)&cosb[cbase + dlo];
        float4 ch = *(const float4*)&cosb[cbase + dlo + 64];
        float4 sl = *(const float4*)&sinb[cbase + dlo];
        float4 sh = *(const float4*)&sinb[cbase + dlo + 64];
        float cla[4] = {cl.x, cl.y, cl.z, cl.w}, cha[4] = {ch.x, ch.y, ch.z, ch.w};
        float sla[4] = {sl.x, sl.y, sl.z, sl.w}, sha[4] = {sh.x, sh.y, sh.z, sh.w};
        half4 olo, ohi;
#pragma unroll
        for (int r = 0; r < 4; ++r) {
          float xl = acc[i][j][r], xh = acc[i][j + 2][r];
          olo[r] = (f16)(xl * cla[r] - xh * sla[r]);
          ohi[r] = (f16)(xh * cha[r] + xl * sha[r]);
        }
        *(half4*)&Dst[obase + dlo] = olo;
        *(half4*)&Dst[obase + dlo + 64] = ohi;
      }
    }
  } else {
    // ---- V: standard K-loop; direct transposed store ----
    for (int k0 = 0; k0 < Kk; k0 += 64) {
      __syncthreads();
      STAGE4(A, abase, k0, As);
      STAGE4(Bt, bbase, k0, Bs);
      STAGE4(A, abase, k0 + 32, (As + 4096));
      STAGE4(Bt, bbase, k0 + 32, (Bs + 4096));
      __syncthreads();
#pragma unroll
      for (int kh = 0; kh < 2; ++kh) {
        const int so = kh * 4096;
        half8 af[4], bf[4];
#pragma unroll
        for (int i = 0; i < 4; ++i) {
          int ra = wm * 64 + i * 16 + lr;
          int rb = wn * 64 + i * 16 + lr;
          af[i] = *(const half8*)&As[so + ra * 32 + ((g ^ (ra & 3)) * 8)];
          bf[i] = *(const half8*)&Bs[so + rb * 32 + ((g ^ (rb & 3)) * 8)];
        }
#pragma unroll
        for (int i = 0; i < 4; ++i)
#pragma unroll
          for (int j = 0; j < 4; ++j)
            acc[i][j] = __builtin_amdgcn_mfma_f32_16x16x32_f16(af[i], bf[j], acc[i][j], 0, 0, 0);
      }
    }
#pragma unroll
    for (int j = 0; j < 4; ++j) {
      int d = wn * 64 + j * 16 + lr;
      size_t rowb = ((size_t)bh * D + d) * S;
#pragma unroll
      for (int i = 0; i < 4; ++i) {
        int s0 = sblk + wm * 64 + i * 16 + g * 4;
        half4 h4;
#pragma unroll
        for (int r = 0; r < 4; ++r) h4[r] = (f16)acc[i][j][r];
        *(half4*)&VtG[rowb + s0] = h4;
      }
    }
  }
}

// ---------- plain GEMM (out-proj): 128x128, BK=64 two-section ----------
template <typename OutT>
__global__ __launch_bounds__(256, 4) void gemm_bt(const f16* __restrict__ A,
                                                  const f16* __restrict__ Bt,
                                                  OutT* __restrict__ C,
                                                  int Mm, int Nn, int Kk) {
  __shared__ f16 As[8192];
  __shared__ f16 Bs[8192];
  const int t = threadIdx.x, l = t & 63;
  const int wm = (t >> 7) & 1, wn = (t >> 6) & 1;
  const int bm = blockIdx.x, bn = blockIdx.y;
  const int lr = l & 15, g = l >> 4;
  const int srow = t >> 2;
  const int scol = (((t & 3) ^ (srow & 3)) * 8);
  const size_t abase = (size_t)(bm * 128 + srow) * Kk;
  const size_t bbase = (size_t)(bn * 128 + srow) * Kk;
  f32x4 acc[4][4] = {};
  for (int k0 = 0; k0 < Kk; k0 += 64) {
    __syncthreads();
    STAGE4(A, abase, k0, As);
    STAGE4(Bt, bbase, k0, Bs);
    STAGE4(A, abase, k0 + 32, (As + 4096));
    STAGE4(Bt, bbase, k0 + 32, (Bs + 4096));
    __syncthreads();
#pragma unroll
    for (int kh = 0; kh < 2; ++kh) {
      const int so = kh * 4096;
      half8 af[4], bf[4];
#pragma unroll
      for (int i = 0; i < 4; ++i) {
        int ra = wm * 64 + i * 16 + lr;
        int rb = wn * 64 + i * 16 + lr;
        af[i] = *(const half8*)&As[so + ra * 32 + ((g ^ (ra & 3)) * 8)];
        bf[i] = *(const half8*)&Bs[so + rb * 32 + ((g ^ (rb & 3)) * 8)];
      }
#pragma unroll
      for (int i = 0; i < 4; ++i)
#pragma unroll
        for (int j = 0; j < 4; ++j)
          acc[i][j] = __builtin_amdgcn_mfma_f32_16x16x32_f16(af[i], bf[j], acc[i][j], 0, 0, 0);
    }
  }
#pragma unroll
  for (int i = 0; i < 4; ++i)
#pragma unroll
    for (int j = 0; j < 4; ++j) {
      int row = bm * 128 + wm * 64 + i * 16 + g * 4;
      int col = bn * 128 + wn * 64 + j * 16 + lr;
#pragma unroll
      for (int r = 0; r < 4; ++r)
        C[(size_t)(row + r) * Nn + col] = (OutT)acc[i][j][r];
    }
}

// ---------- flash attention: 32x32x16, swapped operands ----------
__device__ __forceinline__ void stage_kv(const f16* __restrict__ Kg, const f16* __restrict__ Vg,
                                         f16* KsB, f16* VsB, int t, int kv) {
#pragma unroll
  for (int rnd = 0; rnd < 4; ++rnd) {
    int row = rnd * 16 + (t >> 4);
    int c = t & 15;
    gload_lds16(&Kg[(size_t)(kv + row) * D + ((c ^ (row & 7)) * 8)], &KsB[rnd * 2048 + t * 8]);
  }
#pragma unroll
  for (int rnd = 0; rnd < 4; ++rnd) {
    int row = rnd * 32 + (t >> 3);
    int c = t & 7;
    gload_lds16(&Vg[(size_t)row * S + kv + ((c ^ (row & 7)) * 8)], &VsB[rnd * 2048 + t * 8]);
  }
}

__global__ __launch_bounds__(256, 2) void flash_attn2(const f16* __restrict__ Q,
                                                      const f16* __restrict__ K,
                                                      const f16* __restrict__ Vt,
                                                      f16* __restrict__ O) {
  __shared__ f16 lds[2][16384];
  const int t = threadIdx.x, l = t & 63, w = t >> 6;
  const int c = l & 31, hi = l >> 5;
  int bid = blockIdx.x;
  bid = (bid & 7) * 64 + (bid >> 3);
  const int bh = bid >> 4, qt = bid & 15;
  const size_t baseQ = (size_t)bh * S * D;
  const f16* Kg = K + baseQ;
  const f16* Vg = Vt + (size_t)bh * D * S;
  const int q0 = qt * 128 + w * 32;
  half8 qf[8];
#pragma unroll
  for (int dc = 0; dc < 8; ++dc)
    qf[dc] = *(const half8*)&Q[baseQ + (size_t)(q0 + c) * D + dc * 16 + hi * 8];
  f32x16 o[4] = {};
  float m = -3.0e38f, ssum = 0.f;

  stage_kv(Kg, Vg, &lds[0][0], &lds[0][8192], t, 0);
  __syncthreads();

  for (int it = 0; it < S / 64; ++it) {
    const int cur = it & 1;
    const f16* KsB = &lds[cur][0];
    const f16* VsB = &lds[cur][8192];
    if (it + 1 < S / 64) stage_kv(Kg, Vg, &lds[cur ^ 1][0], &lds[cur ^ 1][8192], t, (it + 1) * 64);

    f32x16 s0 = {}, s1 = {};
    __builtin_amdgcn_s_setprio(1);
#pragma unroll
    for (int dc = 0; dc < 8; ++dc) {
      const int r0 = c, r1 = 32 + c;
      half8 kf0 = *(const half8*)&KsB[r0 * 128 + (((2 * dc + hi) ^ (r0 & 7)) * 8)];
      half8 kf1 = *(const half8*)&KsB[r1 * 128 + (((2 * dc + hi) ^ (r1 & 7)) * 8)];
      s0 = __builtin_amdgcn_mfma_f32_32x32x16_f16(kf0, qf[dc], s0, 0, 0, 0);
      s1 = __builtin_amdgcn_mfma_f32_32x32x16_f16(kf1, qf[dc], s1, 0, 0, 0);
    }
    __builtin_amdgcn_s_setprio(0);

    float tm = s0[0];
#pragma unroll
    for (int r = 1; r < 16; ++r) tm = fmaxf(tm, s0[r]);
#pragma unroll
    for (int r = 0; r < 16; ++r) tm = fmaxf(tm, s1[r]);
    tm = fmaxf(tm, __shfl_xor(tm, 32));
    float mn = fmaxf(m, tm);
    float corr = __expf(m - mn);
    m = mn;
    float ts = 0.f;
#pragma unroll
    for (int r = 0; r < 16; ++r) { s0[r] = __expf(s0[r] - mn); ts += s0[r]; }
#pragma unroll
    for (int r = 0; r < 16; ++r) { s1[r] = __expf(s1[r] - mn); ts += s1[r]; }
    ts += __shfl_xor(ts, 32);
    ssum = ssum * corr + ts;
#pragma unroll
    for (int dt = 0; dt < 4; ++dt)
#pragma unroll
      for (int r = 0; r < 16; ++r) o[dt][r] *= corr;

    half8 pf[4];
#pragma unroll
    for (int ks = 0; ks < 4; ++ks) {
      const int B0 = 2 * (ks & 1), B1 = B0 + 1;
      uint32_t X0, X1, Y0, Y1;
      if (ks < 2) {
        X0 = pkrtz(s0[4 * B0 + 0], s0[4 * B0 + 1]);
        X1 = pkrtz(s0[4 * B0 + 2], s0[4 * B0 + 3]);
        Y0 = pkrtz(s0[4 * B1 + 0], s0[4 * B1 + 1]);
        Y1 = pkrtz(s0[4 * B1 + 2], s0[4 * B1 + 3]);
      } else {
        X0 = pkrtz(s1[4 * B0 + 0], s1[4 * B0 + 1]);
        X1 = pkrtz(s1[4 * B0 + 2], s1[4 * B0 + 3]);
        Y0 = pkrtz(s1[4 * B1 + 0], s1[4 * B1 + 1]);
        Y1 = pkrtz(s1[4 * B1 + 2], s1[4 * B1 + 3]);
      }
      asm volatile("v_permlane32_swap_b32 %0, %1" : "+v"(X0), "+v"(Y0));
      asm volatile("v_permlane32_swap_b32 %0, %1" : "+v"(X1), "+v"(Y1));
      u32x4 pw; pw[0] = X0; pw[1] = X1; pw[2] = Y0; pw[3] = Y1;
      pf[ks] = __builtin_bit_cast(half8, pw);
    }

    __builtin_amdgcn_s_setprio(1);
#pragma unroll
    for (int dt = 0; dt < 4; ++dt) {
      const int row = dt * 32 + c;
#pragma unroll
      for (int ks = 0; ks < 4; ++ks) {
        half8 vf = *(const half8*)&VsB[row * 64 + (((2 * ks + hi) ^ (row & 7)) * 8)];
        o[dt] = __builtin_amdgcn_mfma_f32_32x32x16_f16(vf, pf[ks], o[dt], 0, 0, 0);
      }
    }
    __builtin_amdgcn_s_setprio(0);
    __syncthreads();
  }

  const float inv = 1.f / ssum;
  const int b = bh >> 4, h = bh & 15;
  const size_t orow = ((size_t)(b * S + q0 + c)) * HD + h * D;
#pragma unroll
  for (int dt = 0; dt < 4; ++dt)
#pragma unroll
    for (int b2 = 0; b2 < 4; ++b2) {
      half4 h4;
#pragma unroll
      for (int a = 0; a < 4; ++a) h4[a] = (f16)(o[dt][4 * b2 + a] * inv);
      *(half4*)&O[orow + dt * 32 + 8 * b2 + 4 * hi] = h4;
    }
}

extern "C" void kernel_launch(void* const* d_in, const int* in_sizes, int n_in,
                              void* d_out, int out_size, void* d_ws, size_t ws_size,
                              hipStream_t stream) {
  (void)in_sizes; (void)n_in; (void)out_size; (void)ws_size;
  const float* hs = (const float*)d_in[0];
  const float* cosb = (const float*)d_in[1];
  const float* sinb = (const float*)d_in[2];
  const float* wq = (const float*)d_in[3];
  const float* wk = (const float*)d_in[4];
  const float* wv = (const float*)d_in[5];
  const float* wo = (const float*)d_in[6];
  float* out = (float*)d_out;
  char* ws = (char*)d_ws;
  f16* hs16 = (f16*)(ws);                 // 16M; dead after qkv_fused
  f16* attn = (f16*)(ws);                 // 16M; alias (written by flash)
  f16* wt   = (f16*)(ws + (16u << 20));   // 24M  [6144][2048]
  f16* wot  = (f16*)(ws + (40u << 20));   // 8M   [2048][2048]
  f16* Qb   = (f16*)(ws + (48u << 20));   // 16M  [32][2048][128]
  f16* Kb   = (f16*)(ws + (64u << 20));   // 16M  [32][2048][128]
  f16* VtG  = (f16*)(ws + (80u << 20));   // 16M  [32][128][2048]

  cast_f32_f16<<<dim3(4096), dim3(256), 0, stream>>>(hs, hs16);
  transpose_cast<<<dim3(64, 64, 4), dim3(32, 8), 0, stream>>>(wq, wk, wv, wo, wt, wot);
  qkv_fused<<<dim3(1536), dim3(256), 0, stream>>>(hs16, wt, cosb, sinb, Qb, Kb, VtG);
  flash_attn2<<<dim3(512), dim3(256), 0, stream>>>(Qb, Kb, VtG, attn);
  gemm_bt<float><<<dim3(32, 16), dim3(256), 0, stream>>>(attn, wot, out, M, E, HD);
}

// Round 10
// 274.273 us; speedup vs baseline: 1.1384x; 1.0898x over previous
//
#include <hip/hip_runtime.h>
#include <stdint.h>

typedef _Float16 f16;
typedef _Float16 half8 __attribute__((ext_vector_type(8)));
typedef _Float16 half4 __attribute__((ext_vector_type(4)));
typedef __fp16 fp16x2 __attribute__((ext_vector_type(2)));
typedef float f32x4 __attribute__((ext_vector_type(4)));
typedef float f32x16 __attribute__((ext_vector_type(16)));
typedef uint32_t u32x4 __attribute__((ext_vector_type(4)));

static constexpr int Bsz = 2, S = 2048, E = 2048, H = 16, D = 128;
static constexpr int M = Bsz * S;        // 4096
static constexpr int N_QKV = 3 * H * D;  // 6144
static constexpr int HD = H * D;         // 2048

__device__ __forceinline__ void gload_lds16(const void* gp, void* lp) {
  __builtin_amdgcn_global_load_lds(
      (const __attribute__((address_space(1))) uint32_t*)(uintptr_t)gp,
      (__attribute__((address_space(3))) uint32_t*)(uint32_t)(uintptr_t)lp,
      16, 0, 0);
}

__device__ __forceinline__ uint32_t pkrtz(float a, float b) {
  fp16x2 r = __builtin_amdgcn_cvt_pkrtz(a, b);
  return __builtin_bit_cast(uint32_t, r);
}

// ---------- f32 -> f16 cast ----------
__global__ void cast_f32_f16(const float* __restrict__ in, f16* __restrict__ out) {
  size_t i = (size_t)(blockIdx.x * 256 + threadIdx.x) * 8;
  float4 a = *(const float4*)&in[i];
  float4 b = *(const float4*)&in[i + 4];
  half8 h;
  h[0] = (f16)a.x; h[1] = (f16)a.y; h[2] = (f16)a.z; h[3] = (f16)a.w;
  h[4] = (f16)b.x; h[5] = (f16)b.y; h[6] = (f16)b.z; h[7] = (f16)b.w;
  *(half8*)&out[i] = h;
}

// ---------- transpose 2048x2048 f32 [k][n] -> f16 [n][k] ----------
__global__ void transpose_cast(const float* __restrict__ wq, const float* __restrict__ wk,
                               const float* __restrict__ wv, const float* __restrict__ wo,
                               f16* __restrict__ wt, f16* __restrict__ wot) {
  __shared__ float tile[32][33];
  int z = blockIdx.z;
  const float* src = (z == 0) ? wq : (z == 1) ? wk : (z == 2) ? wv : wo;
  f16* dst = (z == 3) ? wot : wt + (size_t)z * E * HD;
  int bx = blockIdx.x * 32, by = blockIdx.y * 32;
  int tx = threadIdx.x, ty = threadIdx.y;
#pragma unroll
  for (int r = 0; r < 4; ++r)
    tile[ty + r * 8][tx] = src[(size_t)(by + ty + r * 8) * 2048 + bx + tx];
  __syncthreads();
#pragma unroll
  for (int r = 0; r < 4; ++r)
    dst[(size_t)(bx + ty + r * 8) * 2048 + by + tx] = (f16)tile[tx][ty + r * 8];
}

// Staging of one 32-k section.
#define STAGE4(PTR, BASE, KOFF, DST)                                       \
  gload_lds16(&PTR[BASE + (KOFF) + scol], &DST[t * 8]);                    \
  gload_lds16(&PTR[BASE + (size_t)64 * Kk + (KOFF) + scol], &DST[2048 + t * 8]);

// ---------- QKV GEMM (128x128, BK=64) + fused rope/split/v-transpose ----------
// Grid map: xcd = bid&7 owns bm in [xcd*4, xcd*4+4) (A panels 2MB, L2-resident);
// bn streams. bn 0..15: Q; 16..31: K (swapped mfma, rope in-register);
// 32..47: V (direct transposed store).
__global__ __launch_bounds__(256, 4) void qkv_fused(const f16* __restrict__ A,
                                                    const f16* __restrict__ Bt,
                                                    const float* __restrict__ cosb,
                                                    const float* __restrict__ sinb,
                                                    f16* __restrict__ Qb,
                                                    f16* __restrict__ Kb,
                                                    f16* __restrict__ VtG) {
  __shared__ f16 As[8192];  // [2 sections][128][32]
  __shared__ f16 Bs[8192];
  const int Kk = E;
  const int t = threadIdx.x, l = t & 63;
  const int wm = (t >> 7) & 1, wn = (t >> 6) & 1;
  const int lr = l & 15, g = l >> 4;
  const int bid = blockIdx.x;
  const int idx = bid >> 3;
  const int bm = (bid & 7) * 4 + (idx & 3);  // A-panel resident per XCD
  const int bn = idx >> 2;                   // 0..47, streamed
  const int srow = t >> 2;
  const int scol = (((t & 3) ^ (srow & 3)) * 8);
  const size_t abase = (size_t)(bm * 128 + srow) * Kk;
  const size_t bbase = (size_t)(bn * 128 + srow) * Kk;
  const int bt = bn >> 4;       // 0=q 1=k 2=v
  const int h = bn & 15;
  const int b = bm >> 4;
  const int bh = b * 16 + h;
  const int sblk = (bm & 15) * 128;
  f32x4 acc[4][4] = {};

  if (bt < 2) {
    // ---- Q/K: swapped-operand K-loop; wave cols {wn*32, +16, +64, +80} ----
    for (int k0 = 0; k0 < Kk; k0 += 64) {
      __syncthreads();
      STAGE4(A, abase, k0, As);
      STAGE4(Bt, bbase, k0, Bs);
      STAGE4(A, abase, k0 + 32, (As + 4096));
      STAGE4(Bt, bbase, k0 + 32, (Bs + 4096));
      __syncthreads();
#pragma unroll
      for (int kh = 0; kh < 2; ++kh) {
        const int so = kh * 4096;
        half8 af[4], bf[4];
#pragma unroll
        for (int i = 0; i < 4; ++i) {
          int ra = wm * 64 + i * 16 + lr;
          af[i] = *(const half8*)&As[so + ra * 32 + ((g ^ (ra & 3)) * 8)];
        }
#pragma unroll
        for (int j = 0; j < 4; ++j) {
          int rb = wn * 32 + (j & 1) * 16 + (j >> 1) * 64 + lr;
          bf[j] = *(const half8*)&Bs[so + rb * 32 + ((g ^ (rb & 3)) * 8)];
        }
#pragma unroll
        for (int i = 0; i < 4; ++i)
#pragma unroll
          for (int j = 0; j < 4; ++j)
            acc[i][j] = __builtin_amdgcn_mfma_f32_16x16x32_f16(bf[j], af[i], acc[i][j], 0, 0, 0);
      }
    }
    // ---- rope in-register, coalesced half4 stores ----
    f16* Dst = (bt == 0) ? Qb : Kb;
#pragma unroll
    for (int i = 0; i < 4; ++i) {
      const int s = sblk + wm * 64 + i * 16 + lr;
      const size_t obase = ((size_t)bh * S + s) * D;
      const size_t cbase = (size_t)s * D;
#pragma unroll
      for (int j = 0; j < 2; ++j) {
        const int dlo = wn * 32 + j * 16 + g * 4;
        float4 cl = *(const float4*)&cosb[cbase + dlo];
        float4 ch = *(const float4*)&cosb[cbase + dlo + 64];
        float4 sl = *(const float4*)&sinb[cbase + dlo];
        float4 sh = *(const float4*)&sinb[cbase + dlo + 64];
        float cla[4] = {cl.x, cl.y, cl.z, cl.w}, cha[4] = {ch.x, ch.y, ch.z, ch.w};
        float sla[4] = {sl.x, sl.y, sl.z, sl.w}, sha[4] = {sh.x, sh.y, sh.z, sh.w};
        half4 olo, ohi;
#pragma unroll
        for (int r = 0; r < 4; ++r) {
          float xl = acc[i][j][r], xh = acc[i][j + 2][r];
          olo[r] = (f16)(xl * cla[r] - xh * sla[r]);
          ohi[r] = (f16)(xh * cha[r] + xl * sha[r]);
        }
        *(half4*)&Dst[obase + dlo] = olo;
        *(half4*)&Dst[obase + dlo + 64] = ohi;
      }
    }
  } else {
    // ---- V: standard K-loop; direct transposed store ----
    for (int k0 = 0; k0 < Kk; k0 += 64) {
      __syncthreads();
      STAGE4(A, abase, k0, As);
      STAGE4(Bt, bbase, k0, Bs);
      STAGE4(A, abase, k0 + 32, (As + 4096));
      STAGE4(Bt, bbase, k0 + 32, (Bs + 4096));
      __syncthreads();
#pragma unroll
      for (int kh = 0; kh < 2; ++kh) {
        const int so = kh * 4096;
        half8 af[4], bf[4];
#pragma unroll
        for (int i = 0; i < 4; ++i) {
          int ra = wm * 64 + i * 16 + lr;
          int rb = wn * 64 + i * 16 + lr;
          af[i] = *(const half8*)&As[so + ra * 32 + ((g ^ (ra & 3)) * 8)];
          bf[i] = *(const half8*)&Bs[so + rb * 32 + ((g ^ (rb & 3)) * 8)];
        }
#pragma unroll
        for (int i = 0; i < 4; ++i)
#pragma unroll
          for (int j = 0; j < 4; ++j)
            acc[i][j] = __builtin_amdgcn_mfma_f32_16x16x32_f16(af[i], bf[j], acc[i][j], 0, 0, 0);
      }
    }
#pragma unroll
    for (int j = 0; j < 4; ++j) {
      int d = wn * 64 + j * 16 + lr;
      size_t rowb = ((size_t)bh * D + d) * S;
#pragma unroll
      for (int i = 0; i < 4; ++i) {
        int s0 = sblk + wm * 64 + i * 16 + g * 4;
        half4 h4;
#pragma unroll
        for (int r = 0; r < 4; ++r) h4[r] = (f16)acc[i][j][r];
        *(half4*)&VtG[rowb + s0] = h4;
      }
    }
  }
}

// ---------- out-proj GEMM: 128x128 BK=64; bm L2-resident per XCD ----------
template <typename OutT>
__global__ __launch_bounds__(256, 4) void gemm_bt(const f16* __restrict__ A,
                                                  const f16* __restrict__ Bt,
                                                  OutT* __restrict__ C,
                                                  int Nn, int Kk) {
  __shared__ f16 As[8192];
  __shared__ f16 Bs[8192];
  const int t = threadIdx.x, l = t & 63;
  const int wm = (t >> 7) & 1, wn = (t >> 6) & 1;
  const int bid = blockIdx.x;
  const int bm = (bid & 7) * 4 + ((bid >> 3) & 3);  // 0..31
  const int bn = bid >> 5;                          // 0..15
  const int lr = l & 15, g = l >> 4;
  const int srow = t >> 2;
  const int scol = (((t & 3) ^ (srow & 3)) * 8);
  const size_t abase = (size_t)(bm * 128 + srow) * Kk;
  const size_t bbase = (size_t)(bn * 128 + srow) * Kk;
  f32x4 acc[4][4] = {};
  for (int k0 = 0; k0 < Kk; k0 += 64) {
    __syncthreads();
    STAGE4(A, abase, k0, As);
    STAGE4(Bt, bbase, k0, Bs);
    STAGE4(A, abase, k0 + 32, (As + 4096));
    STAGE4(Bt, bbase, k0 + 32, (Bs + 4096));
    __syncthreads();
#pragma unroll
    for (int kh = 0; kh < 2; ++kh) {
      const int so = kh * 4096;
      half8 af[4], bf[4];
#pragma unroll
      for (int i = 0; i < 4; ++i) {
        int ra = wm * 64 + i * 16 + lr;
        int rb = wn * 64 + i * 16 + lr;
        af[i] = *(const half8*)&As[so + ra * 32 + ((g ^ (ra & 3)) * 8)];
        bf[i] = *(const half8*)&Bs[so + rb * 32 + ((g ^ (rb & 3)) * 8)];
      }
#pragma unroll
      for (int i = 0; i < 4; ++i)
#pragma unroll
        for (int j = 0; j < 4; ++j)
          acc[i][j] = __builtin_amdgcn_mfma_f32_16x16x32_f16(af[i], bf[j], acc[i][j], 0, 0, 0);
    }
  }
#pragma unroll
  for (int i = 0; i < 4; ++i)
#pragma unroll
    for (int j = 0; j < 4; ++j) {
      int row = bm * 128 + wm * 64 + i * 16 + g * 4;
      int col = bn * 128 + wn * 64 + j * 16 + lr;
#pragma unroll
      for (int r = 0; r < 4; ++r)
        C[(size_t)(row + r) * Nn + col] = (OutT)acc[i][j][r];
    }
}

// ---------- flash attention: 32x32x16, swapped operands, defer-max ----------
__device__ __forceinline__ void stage_kv(const f16* __restrict__ Kg, const f16* __restrict__ Vg,
                                         f16* KsB, f16* VsB, int t, int kv) {
#pragma unroll
  for (int rnd = 0; rnd < 4; ++rnd) {
    int row = rnd * 16 + (t >> 4);
    int c = t & 15;
    gload_lds16(&Kg[(size_t)(kv + row) * D + ((c ^ (row & 7)) * 8)], &KsB[rnd * 2048 + t * 8]);
  }
#pragma unroll
  for (int rnd = 0; rnd < 4; ++rnd) {
    int row = rnd * 32 + (t >> 3);
    int c = t & 7;
    gload_lds16(&Vg[(size_t)row * S + kv + ((c ^ (row & 7)) * 8)], &VsB[rnd * 2048 + t * 8]);
  }
}

__global__ __launch_bounds__(256, 2) void flash_attn2(const f16* __restrict__ Q,
                                                      const f16* __restrict__ K,
                                                      const f16* __restrict__ Vt,
                                                      f16* __restrict__ O) {
  __shared__ f16 lds[2][16384];
  const int t = threadIdx.x, l = t & 63, w = t >> 6;
  const int c = l & 31, hi = l >> 5;
  int bid = blockIdx.x;
  bid = (bid & 7) * 64 + (bid >> 3);
  const int bh = bid >> 4, qt = bid & 15;
  const size_t baseQ = (size_t)bh * S * D;
  const f16* Kg = K + baseQ;
  const f16* Vg = Vt + (size_t)bh * D * S;
  const int q0 = qt * 128 + w * 32;
  half8 qf[8];
#pragma unroll
  for (int dc = 0; dc < 8; ++dc)
    qf[dc] = *(const half8*)&Q[baseQ + (size_t)(q0 + c) * D + dc * 16 + hi * 8];
  f32x16 o[4] = {};
  float m = -3.0e38f, ssum = 0.f;

  stage_kv(Kg, Vg, &lds[0][0], &lds[0][8192], t, 0);
  __syncthreads();

  for (int it = 0; it < S / 64; ++it) {
    const int cur = it & 1;
    const f16* KsB = &lds[cur][0];
    const f16* VsB = &lds[cur][8192];
    if (it + 1 < S / 64) stage_kv(Kg, Vg, &lds[cur ^ 1][0], &lds[cur ^ 1][8192], t, (it + 1) * 64);

    f32x16 s0 = {}, s1 = {};
    __builtin_amdgcn_s_setprio(1);
#pragma unroll
    for (int dc = 0; dc < 8; ++dc) {
      const int r0 = c, r1 = 32 + c;
      half8 kf0 = *(const half8*)&KsB[r0 * 128 + (((2 * dc + hi) ^ (r0 & 7)) * 8)];
      half8 kf1 = *(const half8*)&KsB[r1 * 128 + (((2 * dc + hi) ^ (r1 & 7)) * 8)];
      s0 = __builtin_amdgcn_mfma_f32_32x32x16_f16(kf0, qf[dc], s0, 0, 0, 0);
      s1 = __builtin_amdgcn_mfma_f32_32x32x16_f16(kf1, qf[dc], s1, 0, 0, 0);
    }
    __builtin_amdgcn_s_setprio(0);

    float tm = s0[0];
#pragma unroll
    for (int r = 1; r < 16; ++r) tm = fmaxf(tm, s0[r]);
#pragma unroll
    for (int r = 0; r < 16; ++r) tm = fmaxf(tm, s1[r]);
    tm = fmaxf(tm, __shfl_xor(tm, 32));
    // defer-max (T13): only rescale when some lane's tile max exceeds m+8
    if (!__all(tm <= m + 8.f)) {
      float mn = fmaxf(m, tm);
      float corr = __expf(m - mn);
      m = mn;
      ssum *= corr;
#pragma unroll
      for (int dt = 0; dt < 4; ++dt)
#pragma unroll
        for (int r = 0; r < 16; ++r) o[dt][r] *= corr;
    }
    float ts = 0.f;
#pragma unroll
    for (int r = 0; r < 16; ++r) { s0[r] = __expf(s0[r] - m); ts += s0[r]; }
#pragma unroll
    for (int r = 0; r < 16; ++r) { s1[r] = __expf(s1[r] - m); ts += s1[r]; }
    ts += __shfl_xor(ts, 32);
    ssum += ts;

    half8 pf[4];
#pragma unroll
    for (int ks = 0; ks < 4; ++ks) {
      const int B0 = 2 * (ks & 1), B1 = B0 + 1;
      uint32_t X0, X1, Y0, Y1;
      if (ks < 2) {
        X0 = pkrtz(s0[4 * B0 + 0], s0[4 * B0 + 1]);
        X1 = pkrtz(s0[4 * B0 + 2], s0[4 * B0 + 3]);
        Y0 = pkrtz(s0[4 * B1 + 0], s0[4 * B1 + 1]);
        Y1 = pkrtz(s0[4 * B1 + 2], s0[4 * B1 + 3]);
      } else {
        X0 = pkrtz(s1[4 * B0 + 0], s1[4 * B0 + 1]);
        X1 = pkrtz(s1[4 * B0 + 2], s1[4 * B0 + 3]);
        Y0 = pkrtz(s1[4 * B1 + 0], s1[4 * B1 + 1]);
        Y1 = pkrtz(s1[4 * B1 + 2], s1[4 * B1 + 3]);
      }
      asm volatile("v_permlane32_swap_b32 %0, %1" : "+v"(X0), "+v"(Y0));
      asm volatile("v_permlane32_swap_b32 %0, %1" : "+v"(X1), "+v"(Y1));
      u32x4 pw; pw[0] = X0; pw[1] = X1; pw[2] = Y0; pw[3] = Y1;
      pf[ks] = __builtin_bit_cast(half8, pw);
    }

    __builtin_amdgcn_s_setprio(1);
#pragma unroll
    for (int dt = 0; dt < 4; ++dt) {
      const int row = dt * 32 + c;
#pragma unroll
      for (int ks = 0; ks < 4; ++ks) {
        half8 vf = *(const half8*)&VsB[row * 64 + (((2 * ks + hi) ^ (row & 7)) * 8)];
        o[dt] = __builtin_amdgcn_mfma_f32_32x32x16_f16(vf, pf[ks], o[dt], 0, 0, 0);
      }
    }
    __builtin_amdgcn_s_setprio(0);
    __syncthreads();
  }

  const float inv = 1.f / ssum;
  const int b = bh >> 4, h = bh & 15;
  const size_t orow = ((size_t)(b * S + q0 + c)) * HD + h * D;
#pragma unroll
  for (int dt = 0; dt < 4; ++dt)
#pragma unroll
    for (int b2 = 0; b2 < 4; ++b2) {
      half4 h4;
#pragma unroll
      for (int a = 0; a < 4; ++a) h4[a] = (f16)(o[dt][4 * b2 + a] * inv);
      *(half4*)&O[orow + dt * 32 + 8 * b2 + 4 * hi] = h4;
    }
}

extern "C" void kernel_launch(void* const* d_in, const int* in_sizes, int n_in,
                              void* d_out, int out_size, void* d_ws, size_t ws_size,
                              hipStream_t stream) {
  (void)in_sizes; (void)n_in; (void)out_size; (void)ws_size;
  const float* hs = (const float*)d_in[0];
  const float* cosb = (const float*)d_in[1];
  const float* sinb = (const float*)d_in[2];
  const float* wq = (const float*)d_in[3];
  const float* wk = (const float*)d_in[4];
  const float* wv = (const float*)d_in[5];
  const float* wo = (const float*)d_in[6];
  float* out = (float*)d_out;
  char* ws = (char*)d_ws;
  f16* hs16 = (f16*)(ws);                 // 16M; dead after qkv_fused
  f16* attn = (f16*)(ws);                 // 16M; alias (written by flash)
  f16* wt   = (f16*)(ws + (16u << 20));   // 24M  [6144][2048]
  f16* wot  = (f16*)(ws + (40u << 20));   // 8M   [2048][2048]
  f16* Qb   = (f16*)(ws + (48u << 20));   // 16M  [32][2048][128]
  f16* Kb   = (f16*)(ws + (64u << 20));   // 16M  [32][2048][128]
  f16* VtG  = (f16*)(ws + (80u << 20));   // 16M  [32][128][2048]

  cast_f32_f16<<<dim3(4096), dim3(256), 0, stream>>>(hs, hs16);
  transpose_cast<<<dim3(64, 64, 4), dim3(32, 8), 0, stream>>>(wq, wk, wv, wo, wt, wot);
  qkv_fused<<<dim3(1536), dim3(256), 0, stream>>>(hs16, wt, cosb, sinb, Qb, Kb, VtG);
  flash_attn2<<<dim3(512), dim3(256), 0, stream>>>(Qb, Kb, VtG, attn);
  gemm_bt<float><<<dim3(512), dim3(256), 0, stream>>>(attn, wot, out, E, HD);
}